// Round 8
// baseline (135.624 us; speedup 1.0000x reference)
//
#include <hip/hip_runtime.h>
#include <hip/hip_bf16.h>

// Problem constants (fixed by the bench): B=2, Tq=Tv=2048, D=512, H=8, dh=64.
// Inputs and output are FLOAT32.
#define BATCH 2
#define TSEQ  2048
#define DMODEL 512
#define NHEAD 8
#define DHEAD 64

typedef __bf16 bf16x2 __attribute__((ext_vector_type(2)));
typedef __bf16 bf16x4 __attribute__((ext_vector_type(4)));
typedef __bf16 bf16x8 __attribute__((ext_vector_type(8)));
typedef float  f32x4  __attribute__((ext_vector_type(4)));

__device__ __forceinline__ bf16x8 load_b8(const void* p) {
  return __builtin_bit_cast(bf16x8, *reinterpret_cast<const uint4*>(p));
}
__device__ __forceinline__ bf16x4 load_b4(const void* p) {
  return __builtin_bit_cast(bf16x4, *reinterpret_cast<const uint2*>(p));
}

// load 8 fp32 and convert to bf16x8 (p must be 16B-aligned)
__device__ __forceinline__ bf16x8 cvt8(const float* p) {
  float4 a = *reinterpret_cast<const float4*>(p);
  float4 b = *reinterpret_cast<const float4*>(p + 4);
  bf16x8 r;
  r[0] = (__bf16)a.x; r[1] = (__bf16)a.y; r[2] = (__bf16)a.z; r[3] = (__bf16)a.w;
  r[4] = (__bf16)b.x; r[5] = (__bf16)b.y; r[6] = (__bf16)b.z; r[7] = (__bf16)b.w;
  return r;
}

// ---------------------------------------------------------------------------
// Kernel 1: K[b][t][o] = sum_d V[b][t][d] * W[o][d] + bias[o]   (conv1d, k=1)
// grid 256 blocks (B * Tv/16), 256 threads; wave w owns 8 of 32 o-tiles.
// ---------------------------------------------------------------------------
__global__ __launch_bounds__(256) void conv_kernel(
    const float* __restrict__ V,
    const float* __restrict__ W,
    const float* __restrict__ bias,
    __hip_bfloat16* __restrict__ K) {
  const int bx = blockIdx.x;
  const int b  = bx >> 7;
  const int t0 = (bx & 127) << 4;
  const int w  = threadIdx.x >> 6;
  const int l  = threadIdx.x & 63;
  const int lm = l & 15;
  const int lg = l >> 4;

  const float* vrow = V + ((size_t)(b * TSEQ + t0 + lm)) * DHEAD;
  bf16x8 av0 = cvt8(vrow + lg * 8);
  bf16x8 av1 = cvt8(vrow + 32 + lg * 8);

  #pragma unroll
  for (int n = 0; n < 8; ++n) {
    const int o0 = (w * 8 + n) * 16;
    const float* wrow = W + ((size_t)(o0 + lm)) * DHEAD;
    bf16x8 b0 = cvt8(wrow + lg * 8);
    bf16x8 b1 = cvt8(wrow + 32 + lg * 8);
    f32x4 acc = {0.f, 0.f, 0.f, 0.f};
    acc = __builtin_amdgcn_mfma_f32_16x16x32_bf16(av0, b0, acc, 0, 0, 0);
    acc = __builtin_amdgcn_mfma_f32_16x16x32_bf16(av1, b1, acc, 0, 0, 0);
    const float bv = bias[o0 + lm];
    #pragma unroll
    for (int r = 0; r < 4; ++r) {
      const int t = t0 + lg * 4 + r;
      K[((size_t)(b * TSEQ + t)) * DMODEL + o0 + lm] =
          __float2bfloat16(acc[r] + bv);
    }
  }
}

// ---------------------------------------------------------------------------
// Kernel 2: Vt[b][d][t] = (bf16) V[b][t][d] via LDS tile transpose.
// grid 64 blocks (B * Tv/64), 256 threads.
// ---------------------------------------------------------------------------
__global__ __launch_bounds__(256) void vt_kernel(const float* __restrict__ V,
                                                 __hip_bfloat16* __restrict__ Vt) {
  const int bx = blockIdx.x;
  const int b  = bx >> 5;
  const int t0 = (bx & 31) << 6;
  const int tid = threadIdx.x;
  __shared__ float tile[64][65];

  #pragma unroll
  for (int p = 0; p < 4; ++p) {
    const int r = p * 16 + (tid >> 4);
    const int c = (tid & 15) * 4;
    float4 v = *reinterpret_cast<const float4*>(
        &V[((size_t)(b * TSEQ + t0 + r)) * DHEAD + c]);
    tile[r][c]     = v.x;
    tile[r][c + 1] = v.y;
    tile[r][c + 2] = v.z;
    tile[r][c + 3] = v.w;
  }
  __syncthreads();

  const int d  = tid >> 2;
  const int ts = (tid & 3) * 16;
  uint u[8];
  #pragma unroll
  for (int j = 0; j < 8; ++j) {
    bf16x2 p2;
    p2[0] = (__bf16)tile[ts + 2 * j][d];
    p2[1] = (__bf16)tile[ts + 2 * j + 1][d];
    u[j] = __builtin_bit_cast(uint, p2);
  }
  uint4* dst = reinterpret_cast<uint4*>(
      Vt + ((size_t)(b * DHEAD + d)) * TSEQ + t0 + ts);
  dst[0] = uint4{u[0], u[1], u[2], u[3]};
  dst[1] = uint4{u[4], u[5], u[6], u[7]};
}

// ---------------------------------------------------------------------------
// Kernel 3: fused attention, softmax over HEADS (lane-local), barrier-free
// k-loop. grid 256 blocks = B * (Tq/16), 1 block/CU, XCD-swizzled.
//
// REGISTER BUDGET (rounds 5-7 lesson): the working set is ~290 total regs
// (accO 128 + sv 32 + wf 32 + qf 64 + transients). A 512-thread block forces
// 2 waves/SIMD by shape alone -> per-wave cap 256 (VGPR+AGPR) -> guaranteed
// spill (83-162 MB scratch HBM traffic, VALUBusy <1%). So: 256 threads
// (4 waves), 1 block/CU, 1 wave/SIMD -> 512-slot budget. Q fragments hoisted
// to registers (no LDS Q tile, no in-loop barriers at all). Each wave owns a
// 512-k strip; 4 partial O^T are reduced via LDS in the epilogue.
// ---------------------------------------------------------------------------
__global__ __launch_bounds__(256, 1) void attn_kernel(
    const float* __restrict__ Q,
    const __hip_bfloat16* __restrict__ K,
    const __hip_bfloat16* __restrict__ Vt,
    float* __restrict__ Out) {
  // XCD swizzle: 256 blocks, 8 XCDs -> XCD x gets logical blocks [x*32, x*32+32)
  const int bx = blockIdx.x;
  const int L  = (bx & 7) * 32 + (bx >> 3);
  const int b  = L >> 7;
  const int q0 = (L & 127) << 4;
  const int tid = threadIdx.x;
  const int w  = tid >> 6;            // 0..3
  const int l  = tid & 63;
  const int lm = l & 15;
  const int lg = l >> 4;

  __shared__ float Obuf[4][64][17];   // [wave][d][q+pad] reduction buffer

  // ---- Q fragments resident in registers (one-time global read) ----
  // B-operand layout for mfma(K,Q): n=q -> lane&15, kk-dim -> (lane>>4)*8+j.
  bf16x8 qf[NHEAD][2];
  {
    const float* qrow = Q + ((size_t)(b * TSEQ + q0 + lm)) * DMODEL + lg * 8;
    #pragma unroll
    for (int h = 0; h < NHEAD; ++h) {
      qf[h][0] = cvt8(qrow + h * DHEAD);
      qf[h][1] = cvt8(qrow + h * DHEAD + 32);
    }
  }

  f32x4 accO[NHEAD][4];   // [h][dt], O^T: d = dt*16 + lg*4 + r, q = lm
  #pragma unroll
  for (int h = 0; h < NHEAD; ++h)
    #pragma unroll
    for (int j = 0; j < 4; ++j) accO[h][j] = (f32x4){0.f, 0.f, 0.f, 0.f};

  const float cl2 = 0.125f * 1.44269504f;   // dh^-0.5 * log2(e)

  #pragma unroll 2
  for (int pr = 0; pr < 16; ++pr) {
    const int kset0 = w * 512 + pr * 32;
    bf16x8 wf[NHEAD];                  // normalized weights, B-frag layout

    #pragma unroll
    for (int s2 = 0; s2 < 2; ++s2) {
      const int kset = kset0 + s2 * 16;
      f32x4 sv[NHEAD];
      const __hip_bfloat16* kbase =
          K + ((size_t)(b * TSEQ + kset + lm)) * DMODEL + lg * 8;
      #pragma unroll
      for (int h = 0; h < NHEAD; ++h) {
        bf16x8 kf0 = load_b8(kbase + h * DHEAD);
        bf16x8 kf1 = load_b8(kbase + h * DHEAD + 32);
        f32x4 t = {0.f, 0.f, 0.f, 0.f};
        t = __builtin_amdgcn_mfma_f32_16x16x32_bf16(kf0, qf[h][0], t, 0, 0, 0);
        t = __builtin_amdgcn_mfma_f32_16x16x32_bf16(kf1, qf[h][1], t, 0, 0, 0);
        sv[h] = t;
      }
      // softmax over heads (lane-local), per k-slot r
      #pragma unroll
      for (int r = 0; r < 4; ++r) {
        float v[NHEAD];
        #pragma unroll
        for (int h = 0; h < NHEAD; ++h) v[h] = sv[h][r] * cl2;
        float m = fmaxf(fmaxf(fmaxf(v[0], v[1]), fmaxf(v[2], v[3])),
                        fmaxf(fmaxf(v[4], v[5]), fmaxf(v[6], v[7])));
        float e[NHEAD];
        float sum = 0.f;
        #pragma unroll
        for (int h = 0; h < NHEAD; ++h) { e[h] = exp2f(v[h] - m); sum += e[h]; }
        const float inv = __builtin_amdgcn_rcpf(sum);
        #pragma unroll
        for (int h = 0; h < NHEAD; ++h)
          wf[h][s2 * 4 + r] = (__bf16)(e[h] * inv);
      }
    }

    // ---- PV: O^T[d][q] += sum_k V[k][d] * w[q][k], K=32 over the pair ----
    const __hip_bfloat16* vbase =
        Vt + ((size_t)(b * DHEAD + lm)) * TSEQ + kset0 + lg * 4;
    #pragma unroll
    for (int dt = 0; dt < 4; ++dt) {
      bf16x4 v0 = load_b4(vbase + (size_t)dt * 16 * TSEQ);
      bf16x4 v1 = load_b4(vbase + (size_t)dt * 16 * TSEQ + 16);
      bf16x8 vf;
      #pragma unroll
      for (int j = 0; j < 4; ++j) { vf[j] = v0[j]; vf[j + 4] = v1[j]; }
      #pragma unroll
      for (int h = 0; h < NHEAD; ++h)
        accO[h][dt] = __builtin_amdgcn_mfma_f32_16x16x32_bf16(vf, wf[h], accO[h][dt], 0, 0, 0);
    }
  }

  // ---- epilogue: reduce 4 k-strip waves via LDS, one head per round.
  //      FULLY UNROLLED so accO indexing stays compile-time (stays in regs).
  #pragma unroll
  for (int h = 0; h < NHEAD; ++h) {
    #pragma unroll
    for (int dt = 0; dt < 4; ++dt)
      #pragma unroll
      for (int r = 0; r < 4; ++r)
        Obuf[w][dt * 16 + lg * 4 + r][lm] = accO[h][dt][r];
    __syncthreads();

    {
      const int q  = tid >> 4;         // 0..15
      const int d0 = (tid & 15) * 4;   // 4 d per thread
      float4 s = {0.f, 0.f, 0.f, 0.f};
      #pragma unroll
      for (int ww = 0; ww < 4; ++ww) {
        s.x += Obuf[ww][d0][q];
        s.y += Obuf[ww][d0 + 1][q];
        s.z += Obuf[ww][d0 + 2][q];
        s.w += Obuf[ww][d0 + 3][q];
      }
      *reinterpret_cast<float4*>(
          &Out[((size_t)(b * TSEQ + q0 + q)) * DMODEL + h * DHEAD + d0]) = s;
    }
    __syncthreads();
  }
}

// ---------------------------------------------------------------------------
extern "C" void kernel_launch(void* const* d_in, const int* in_sizes, int n_in,
                              void* d_out, int out_size, void* d_ws, size_t ws_size,
                              hipStream_t stream) {
  const float* Q    = (const float*)d_in[0];
  const float* V    = (const float*)d_in[1];
  const float* W    = (const float*)d_in[2];
  const float* bias = (const float*)d_in[3];
  float* Out = (float*)d_out;

  // ws layout: K bf16 [2][2048][512] (4 MiB) | Vt bf16 [2][64][2048] (0.5 MiB)
  __hip_bfloat16* Kbuf = (__hip_bfloat16*)d_ws;
  __hip_bfloat16* Vt   = Kbuf + (size_t)BATCH * TSEQ * DMODEL;

  conv_kernel<<<256, 256, 0, stream>>>(V, W, bias, Kbuf);
  vt_kernel<<<64, 256, 0, stream>>>(V, Vt);
  attn_kernel<<<BATCH * (TSEQ / 16), 256, 0, stream>>>(Q, Kbuf, Vt, Out);
}

// Round 9
// 93.731 us; speedup vs baseline: 1.4469x; 1.4469x over previous
//
#include <hip/hip_runtime.h>
#include <hip/hip_bf16.h>

// Problem constants (fixed by the bench): B=2, Tq=Tv=2048, D=512, H=8, dh=64.
// Inputs and output are FLOAT32.
#define BATCH 2
#define TSEQ  2048
#define DMODEL 512
#define NHEAD 8
#define DHEAD 64

typedef __bf16 bf16x2 __attribute__((ext_vector_type(2)));
typedef __bf16 bf16x4 __attribute__((ext_vector_type(4)));
typedef __bf16 bf16x8 __attribute__((ext_vector_type(8)));
typedef float  f32x4  __attribute__((ext_vector_type(4)));

__device__ __forceinline__ bf16x8 load_b8(const void* p) {
  return __builtin_bit_cast(bf16x8, *reinterpret_cast<const uint4*>(p));
}
__device__ __forceinline__ bf16x4 load_b4(const void* p) {
  return __builtin_bit_cast(bf16x4, *reinterpret_cast<const uint2*>(p));
}

// load 8 fp32 and convert to bf16x8 (p must be 16B-aligned)
__device__ __forceinline__ bf16x8 cvt8(const float* p) {
  float4 a = *reinterpret_cast<const float4*>(p);
  float4 b = *reinterpret_cast<const float4*>(p + 4);
  bf16x8 r;
  r[0] = (__bf16)a.x; r[1] = (__bf16)a.y; r[2] = (__bf16)a.z; r[3] = (__bf16)a.w;
  r[4] = (__bf16)b.x; r[5] = (__bf16)b.y; r[6] = (__bf16)b.z; r[7] = (__bf16)b.w;
  return r;
}

// ---------------------------------------------------------------------------
// Kernel 1: K[b][t][o] = sum_d V[b][t][d] * W[o][d] + bias[o]   (conv1d, k=1)
// ---------------------------------------------------------------------------
__global__ __launch_bounds__(256) void conv_kernel(
    const float* __restrict__ V,
    const float* __restrict__ W,
    const float* __restrict__ bias,
    __hip_bfloat16* __restrict__ K) {
  const int bx = blockIdx.x;
  const int b  = bx >> 7;
  const int t0 = (bx & 127) << 4;
  const int w  = threadIdx.x >> 6;
  const int l  = threadIdx.x & 63;
  const int lm = l & 15;
  const int lg = l >> 4;

  const float* vrow = V + ((size_t)(b * TSEQ + t0 + lm)) * DHEAD;
  bf16x8 av0 = cvt8(vrow + lg * 8);
  bf16x8 av1 = cvt8(vrow + 32 + lg * 8);

  #pragma unroll
  for (int n = 0; n < 8; ++n) {
    const int o0 = (w * 8 + n) * 16;
    const float* wrow = W + ((size_t)(o0 + lm)) * DHEAD;
    bf16x8 b0 = cvt8(wrow + lg * 8);
    bf16x8 b1 = cvt8(wrow + 32 + lg * 8);
    f32x4 acc = {0.f, 0.f, 0.f, 0.f};
    acc = __builtin_amdgcn_mfma_f32_16x16x32_bf16(av0, b0, acc, 0, 0, 0);
    acc = __builtin_amdgcn_mfma_f32_16x16x32_bf16(av1, b1, acc, 0, 0, 0);
    const float bv = bias[o0 + lm];
    #pragma unroll
    for (int r = 0; r < 4; ++r) {
      const int t = t0 + lg * 4 + r;
      K[((size_t)(b * TSEQ + t)) * DMODEL + o0 + lm] =
          __float2bfloat16(acc[r] + bv);
    }
  }
}

// ---------------------------------------------------------------------------
// Kernel 2: Vt[b][d][t] = (bf16) V[b][t][d] via LDS tile transpose.
// ---------------------------------------------------------------------------
__global__ __launch_bounds__(256) void vt_kernel(const float* __restrict__ V,
                                                 __hip_bfloat16* __restrict__ Vt) {
  const int bx = blockIdx.x;
  const int b  = bx >> 5;
  const int t0 = (bx & 31) << 6;
  const int tid = threadIdx.x;
  __shared__ float tile[64][65];

  #pragma unroll
  for (int p = 0; p < 4; ++p) {
    const int r = p * 16 + (tid >> 4);
    const int c = (tid & 15) * 4;
    float4 v = *reinterpret_cast<const float4*>(
        &V[((size_t)(b * TSEQ + t0 + r)) * DHEAD + c]);
    tile[r][c]     = v.x;
    tile[r][c + 1] = v.y;
    tile[r][c + 2] = v.z;
    tile[r][c + 3] = v.w;
  }
  __syncthreads();

  const int d  = tid >> 2;
  const int ts = (tid & 3) * 16;
  uint u[8];
  #pragma unroll
  for (int j = 0; j < 8; ++j) {
    bf16x2 p2;
    p2[0] = (__bf16)tile[ts + 2 * j][d];
    p2[1] = (__bf16)tile[ts + 2 * j + 1][d];
    u[j] = __builtin_bit_cast(uint, p2);
  }
  uint4* dst = reinterpret_cast<uint4*>(
      Vt + ((size_t)(b * DHEAD + d)) * TSEQ + t0 + ts);
  dst[0] = uint4{u[0], u[1], u[2], u[3]};
  dst[1] = uint4{u[4], u[5], u[6], u[7]};
}

// ---------------------------------------------------------------------------
// Kernel 3: fused attention, softmax over HEADS (lane-local), barrier-free
// k-loop, EXPLICIT SOFTWARE PIPELINE.
// grid 256 blocks = B * (Tq/16), 1 block/CU, XCD-swizzled; 256 threads =
// 4 waves, 1 wave/SIMD (the no-spill config from round 8: VGPR cap 512).
//
// Round-8 lesson: HBM traffic ideal, no spill, yet 21.6K cyc per 32-k
// iteration vs ~1K compute floor -> exposed L2 latency, zero MLP across the
// load->S->softmax->load->PV phase chain (no other wave to cover it at
// 1 wave/SIMD). Fix: issue next half-tile's K loads and next iteration's V
// loads BEFORE consuming the current named buffer (T14 issue-early pattern),
// giving every load a full compute phase (~1K cyc) to land. All buffers are
// named variables; pr-loop manually unrolled x2 so buffer swap is static.
// ---------------------------------------------------------------------------
__global__ __launch_bounds__(256, 1) void attn_kernel(
    const float* __restrict__ Q,
    const __hip_bfloat16* __restrict__ K,
    const __hip_bfloat16* __restrict__ Vt,
    float* __restrict__ Out) {
  // XCD swizzle: blocks bx%8==x -> XCD x; XCDs 0-3 get batch 0, 4-7 batch 1,
  // so each XCD's L2 holds only its batch's K (2 MiB < 4 MiB).
  const int bx = blockIdx.x;
  const int L  = (bx & 7) * 32 + (bx >> 3);
  const int b  = L >> 7;
  const int q0 = (L & 127) << 4;
  const int tid = threadIdx.x;
  const int w  = tid >> 6;            // 0..3
  const int l  = tid & 63;
  const int lm = l & 15;
  const int lg = l >> 4;

  __shared__ float Obuf[4][64][17];   // [wave][d][q+pad] reduction buffer

  // ---- Q fragments resident in registers (one-time global read) ----
  bf16x8 qf[NHEAD][2];
  {
    const float* qrow = Q + ((size_t)(b * TSEQ + q0 + lm)) * DMODEL + lg * 8;
    #pragma unroll
    for (int h = 0; h < NHEAD; ++h) {
      qf[h][0] = cvt8(qrow + h * DHEAD);
      qf[h][1] = cvt8(qrow + h * DHEAD + 32);
    }
  }

  f32x4 accO[NHEAD][4];   // [h][dt], O^T: d = dt*16 + lg*4 + r, q = lm
  #pragma unroll
  for (int h = 0; h < NHEAD; ++h)
    #pragma unroll
    for (int j = 0; j < 4; ++j) accO[h][j] = (f32x4){0.f, 0.f, 0.f, 0.f};

  const float cl2 = 0.125f * 1.44269504f;   // dh^-0.5 * log2(e)
  const int kw = w * 512;                    // this wave's k-strip base

  // Pipeline buffers (all statically named/indexed).
  bf16x8 kbA[NHEAD][2], kbB[NHEAD][2];       // K half-tile double buffer
  bf16x4 va0[4], va1[4], vb0[4], vb1[4];     // V iteration double buffer

  #define LOAD_KHALF(buf, kset)                                               \
    {                                                                         \
      const __hip_bfloat16* kb_ =                                             \
          K + ((size_t)(b * TSEQ + (kset) + lm)) * DMODEL + lg * 8;           \
      _Pragma("unroll")                                                       \
      for (int h = 0; h < NHEAD; ++h) {                                       \
        buf[h][0] = load_b8(kb_ + h * DHEAD);                                 \
        buf[h][1] = load_b8(kb_ + h * DHEAD + 32);                            \
      }                                                                       \
    }

  #define LOAD_V(v0_, v1_, kset0)                                             \
    {                                                                         \
      const __hip_bfloat16* vb_ =                                             \
          Vt + ((size_t)(b * DHEAD + lm)) * TSEQ + (kset0) + lg * 4;          \
      _Pragma("unroll")                                                       \
      for (int dt = 0; dt < 4; ++dt) {                                        \
        v0_[dt] = load_b4(vb_ + (size_t)dt * 16 * TSEQ);                      \
        v1_[dt] = load_b4(vb_ + (size_t)dt * 16 * TSEQ + 16);                 \
      }                                                                       \
    }

  // S half: MFMA from kbuf+qf, heads-softmax, write wf slots [s2*4 .. s2*4+3]
  #define S_HALF(kbuf, s2)                                                    \
    {                                                                         \
      f32x4 sv[NHEAD];                                                        \
      _Pragma("unroll")                                                       \
      for (int h = 0; h < NHEAD; ++h) {                                       \
        f32x4 t = {0.f, 0.f, 0.f, 0.f};                                       \
        t = __builtin_amdgcn_mfma_f32_16x16x32_bf16(kbuf[h][0], qf[h][0], t, 0, 0, 0); \
        t = __builtin_amdgcn_mfma_f32_16x16x32_bf16(kbuf[h][1], qf[h][1], t, 0, 0, 0); \
        sv[h] = t;                                                            \
      }                                                                       \
      _Pragma("unroll")                                                       \
      for (int r = 0; r < 4; ++r) {                                           \
        float v_[NHEAD];                                                      \
        _Pragma("unroll")                                                     \
        for (int h = 0; h < NHEAD; ++h) v_[h] = sv[h][r] * cl2;               \
        float m_ = fmaxf(fmaxf(fmaxf(v_[0], v_[1]), fmaxf(v_[2], v_[3])),     \
                         fmaxf(fmaxf(v_[4], v_[5]), fmaxf(v_[6], v_[7])));    \
        float e_[NHEAD];                                                      \
        float sum_ = 0.f;                                                     \
        _Pragma("unroll")                                                     \
        for (int h = 0; h < NHEAD; ++h) { e_[h] = exp2f(v_[h] - m_); sum_ += e_[h]; } \
        const float inv_ = __builtin_amdgcn_rcpf(sum_);                       \
        _Pragma("unroll")                                                     \
        for (int h = 0; h < NHEAD; ++h)                                       \
          wf[h][(s2) * 4 + r] = (__bf16)(e_[h] * inv_);                       \
      }                                                                       \
    }

  // One 32-k iteration. Consumes K from kbA (s2=0) and kbB (s2=1), V from
  // (VA0,VA1); prefetches kbB(this pr s2=1), kbA(next pr s2=0), VB(next pr).
  #define PRBODY(PR, VA0, VA1, VB0, VB1)                                      \
    {                                                                         \
      const int kset0 = kw + (PR) * 32;                                       \
      const int knext = kw + ((PR) < 15 ? (PR) + 1 : 15) * 32;                \
      bf16x8 wf[NHEAD];                                                       \
      LOAD_KHALF(kbB, kset0 + 16);      /* issue: this pr, s2=1 */            \
      S_HALF(kbA, 0);                   /* consume kbA */                     \
      LOAD_KHALF(kbA, knext);           /* issue: next pr, s2=0 */            \
      S_HALF(kbB, 1);                   /* consume kbB */                     \
      LOAD_V(VB0, VB1, knext);          /* issue: next pr V */                \
      _Pragma("unroll")                                                       \
      for (int dt = 0; dt < 4; ++dt) {  /* consume VA */                      \
        bf16x8 vf;                                                            \
        _Pragma("unroll")                                                     \
        for (int j = 0; j < 4; ++j) { vf[j] = VA0[dt][j]; vf[j + 4] = VA1[dt][j]; } \
        _Pragma("unroll")                                                     \
        for (int h = 0; h < NHEAD; ++h)                                       \
          accO[h][dt] = __builtin_amdgcn_mfma_f32_16x16x32_bf16(vf, wf[h], accO[h][dt], 0, 0, 0); \
      }                                                                       \
    }

  // prologue: fill kbA and VA for pr=0
  LOAD_KHALF(kbA, kw);
  LOAD_V(va0, va1, kw);

  #pragma unroll 1
  for (int prp = 0; prp < 8; ++prp) {
    PRBODY(2 * prp,     va0, va1, vb0, vb1);
    PRBODY(2 * prp + 1, vb0, vb1, va0, va1);
  }

  #undef PRBODY
  #undef S_HALF
  #undef LOAD_V
  #undef LOAD_KHALF

  // ---- epilogue: reduce 4 k-strip waves via LDS, one head per round.
  //      FULLY UNROLLED so accO indexing stays compile-time.
  #pragma unroll
  for (int h = 0; h < NHEAD; ++h) {
    #pragma unroll
    for (int dt = 0; dt < 4; ++dt)
      #pragma unroll
      for (int r = 0; r < 4; ++r)
        Obuf[w][dt * 16 + lg * 4 + r][lm] = accO[h][dt][r];
    __syncthreads();

    {
      const int q  = tid >> 4;         // 0..15
      const int d0 = (tid & 15) * 4;   // 4 d per thread
      float4 s = {0.f, 0.f, 0.f, 0.f};
      #pragma unroll
      for (int ww = 0; ww < 4; ++ww) {
        s.x += Obuf[ww][d0][q];
        s.y += Obuf[ww][d0 + 1][q];
        s.z += Obuf[ww][d0 + 2][q];
        s.w += Obuf[ww][d0 + 3][q];
      }
      *reinterpret_cast<float4*>(
          &Out[((size_t)(b * TSEQ + q0 + q)) * DMODEL + h * DHEAD + d0]) = s;
    }
    __syncthreads();
  }
}

// ---------------------------------------------------------------------------
extern "C" void kernel_launch(void* const* d_in, const int* in_sizes, int n_in,
                              void* d_out, int out_size, void* d_ws, size_t ws_size,
                              hipStream_t stream) {
  const float* Q    = (const float*)d_in[0];
  const float* V    = (const float*)d_in[1];
  const float* W    = (const float*)d_in[2];
  const float* bias = (const float*)d_in[3];
  float* Out = (float*)d_out;

  // ws layout: K bf16 [2][2048][512] (4 MiB) | Vt bf16 [2][64][2048] (0.5 MiB)
  __hip_bfloat16* Kbuf = (__hip_bfloat16*)d_ws;
  __hip_bfloat16* Vt   = Kbuf + (size_t)BATCH * TSEQ * DMODEL;

  conv_kernel<<<256, 256, 0, stream>>>(V, W, bias, Kbuf);
  vt_kernel<<<64, 256, 0, stream>>>(V, Vt);
  attn_kernel<<<BATCH * (TSEQ / 16), 256, 0, stream>>>(Q, Kbuf, Vt, Out);
}